// Round 1
// baseline (381.041 us; speedup 1.0000x reference)
//
#include <hip/hip_runtime.h>

// Problem constants (match reference: B=32, T=2048, D_IN=1024, D_OUT=256)
constexpr int Bn = 32;
constexpr int Tn = 2048;
constexpr int Dn = 1024;   // D_IN
constexpr int On = 256;    // D_OUT
constexpr int TCH = 64;            // t-chunks per sample
constexpr int CHUNK = Tn / TCH;    // 32 frames per chunk

// Kernel 1: per-sample, zero the accumulator s[b,:] and find length[b].
// length = (first t with mask<0) + 1, or T if none.
__global__ void __launch_bounds__(256) k_prep(const float* __restrict__ mask,
                                              int* __restrict__ len,
                                              float* __restrict__ s) {
    const int b   = blockIdx.x;
    const int tid = threadIdx.x;

    // zero s[b, tid*4 .. tid*4+3]
    reinterpret_cast<float4*>(s + (size_t)b * Dn)[tid] = make_float4(0.f, 0.f, 0.f, 0.f);

    int m = Tn;  // sentinel: no negative found
    const float* mrow = mask + (size_t)b * Tn;
    for (int t = tid; t < Tn; t += 256) {
        if (mrow[t] < 0.0f) m = min(m, t);
    }
    __shared__ int red[256];
    red[tid] = m;
    __syncthreads();
    for (int off = 128; off > 0; off >>= 1) {
        if (tid < off) red[tid] = min(red[tid], red[tid + off]);
        __syncthreads();
    }
    if (tid == 0) len[b] = (red[0] >= Tn) ? Tn : (red[0] + 1);
}

// Kernel 2: s[b,d] += sum over a 32-frame chunk of relu(feature[b,t,d]).
// Block = (b, chunk). 256 threads x float4 covers all D_IN=1024 columns.
// Streams contiguous 4KB rows; early-exit for chunks beyond len[b].
__global__ void __launch_bounds__(256) k_sum(const float* __restrict__ feat,
                                             const int* __restrict__ len,
                                             float* __restrict__ s) {
    const int blk = blockIdx.x;
    const int b   = blk / TCH;
    const int c   = blk % TCH;
    const int L   = len[b];
    const int t0  = c * CHUNK;
    if (t0 >= L) return;                      // fully-masked chunk: skip (s pre-zeroed)
    const int t1  = min(t0 + CHUNK, L);
    const int tid = threadIdx.x;

    const float4* f = reinterpret_cast<const float4*>(feat + (size_t)b * Tn * Dn) + tid;
    float4 acc = make_float4(0.f, 0.f, 0.f, 0.f);
    for (int t = t0; t < t1; ++t) {
        float4 v = f[(size_t)t * (Dn / 4)];
        acc.x += fmaxf(v.x, 0.f);
        acc.y += fmaxf(v.y, 0.f);
        acc.z += fmaxf(v.z, 0.f);
        acc.w += fmaxf(v.w, 0.f);
    }
    float* sp = s + (size_t)b * Dn + tid * 4;
    atomicAdd(sp + 0, acc.x);
    atomicAdd(sp + 1, acc.y);
    atomicAdd(sp + 2, acc.z);
    atomicAdd(sp + 3, acc.w);
}

// Kernel 3: out[b,o] = (s[b,:] . W[o,:]) / len[b] + bias[o].
// One block per sample; s row staged in LDS (broadcast reads -> no conflicts).
__global__ void __launch_bounds__(256) k_out(const float* __restrict__ s,
                                             const int* __restrict__ len,
                                             const float* __restrict__ W,
                                             const float* __restrict__ bias,
                                             float* __restrict__ out) {
    const int b = blockIdx.x;
    const int o = threadIdx.x;

    __shared__ float4 sl[Dn / 4];
    sl[o] = reinterpret_cast<const float4*>(s + (size_t)b * Dn)[o];
    __syncthreads();

    const float4* w = reinterpret_cast<const float4*>(W + (size_t)o * Dn);
    float acc = 0.f;
#pragma unroll 8
    for (int i = 0; i < Dn / 4; ++i) {
        const float4 wv = w[i];
        const float4 sv = sl[i];
        acc += wv.x * sv.x + wv.y * sv.y + wv.z * sv.z + wv.w * sv.w;
    }
    const float inv = 1.0f / (float)len[b];
    out[(size_t)b * On + o] = acc * inv + bias[o];
}

extern "C" void kernel_launch(void* const* d_in, const int* in_sizes, int n_in,
                              void* d_out, int out_size, void* d_ws, size_t ws_size,
                              hipStream_t stream) {
    const float* feat = (const float*)d_in[0];  // [B,T,D_IN] f32
    const float* mask = (const float*)d_in[1];  // [B,T] f32
    const float* W    = (const float*)d_in[2];  // [D_OUT,D_IN] f32
    const float* bias = (const float*)d_in[3];  // [D_OUT] f32
    float* out = (float*)d_out;                 // [B,D_OUT] f32

    // ws layout: [int len[32]] (128 B, padded to 256) | [float s[32*1024]] (128 KB)
    int*   len = (int*)d_ws;
    float* s   = (float*)((char*)d_ws + 256);

    k_prep<<<Bn, 256, 0, stream>>>(mask, len, s);
    k_sum<<<Bn * TCH, 256, 0, stream>>>(feat, len, s);
    k_out<<<Bn, 256, 0, stream>>>(s, len, W, bias, out);
}

// Round 2
// 346.199 us; speedup vs baseline: 1.1006x; 1.1006x over previous
//
#include <hip/hip_runtime.h>

// Problem constants (match reference: B=32, T=2048, D_IN=1024, D_OUT=256)
constexpr int Bn = 32;
constexpr int Tn = 2048;
constexpr int Dn = 1024;   // D_IN
constexpr int On = 256;    // D_OUT
constexpr int TCH = 64;            // t-chunks per sample
constexpr int CHUNK = Tn / TCH;    // 32 frames per chunk

// Kernel 1: per-sample, zero the accumulator s[b,:] and find length[b].
// length = (first t with mask<0) + 1, or T if none.
__global__ void __launch_bounds__(256) k_prep(const float* __restrict__ mask,
                                              int* __restrict__ len,
                                              float* __restrict__ s) {
    const int b   = blockIdx.x;
    const int tid = threadIdx.x;

    // zero s[b, tid*4 .. tid*4+3]
    reinterpret_cast<float4*>(s + (size_t)b * Dn)[tid] = make_float4(0.f, 0.f, 0.f, 0.f);

    int m = Tn;  // sentinel: no negative found
    const float* mrow = mask + (size_t)b * Tn;
    for (int t = tid; t < Tn; t += 256) {
        if (mrow[t] < 0.0f) m = min(m, t);
    }
    __shared__ int red[256];
    red[tid] = m;
    __syncthreads();
    for (int off = 128; off > 0; off >>= 1) {
        if (tid < off) red[tid] = min(red[tid], red[tid + off]);
        __syncthreads();
    }
    if (tid == 0) len[b] = (red[0] >= Tn) ? Tn : (red[0] + 1);
}

// Kernel 2: s[b,d] += sum over a 32-frame chunk of relu(feature[b,t,d]).
// Block = (b, chunk). 256 threads x float4 covers all D_IN=1024 columns.
// Streams contiguous 4KB rows; early-exit for chunks beyond len[b].
// Full chunks take an unroll-8 path (8 outstanding loads/lane).
__global__ void __launch_bounds__(256) k_sum(const float* __restrict__ feat,
                                             const int* __restrict__ len,
                                             float* __restrict__ s) {
    const int blk = blockIdx.x;
    const int b   = blk / TCH;
    const int c   = blk % TCH;
    const int L   = len[b];
    const int t0  = c * CHUNK;
    if (t0 >= L) return;                      // fully-masked chunk: skip (s pre-zeroed)
    const int t1  = min(t0 + CHUNK, L);
    const int tid = threadIdx.x;

    const float4* f = reinterpret_cast<const float4*>(feat + (size_t)b * Tn * Dn) + tid;
    float4 acc = make_float4(0.f, 0.f, 0.f, 0.f);
    if (t1 - t0 == CHUNK) {
#pragma unroll 8
        for (int i = 0; i < CHUNK; ++i) {
            float4 v = f[(size_t)(t0 + i) * (Dn / 4)];
            acc.x += fmaxf(v.x, 0.f);
            acc.y += fmaxf(v.y, 0.f);
            acc.z += fmaxf(v.z, 0.f);
            acc.w += fmaxf(v.w, 0.f);
        }
    } else {
        for (int t = t0; t < t1; ++t) {
            float4 v = f[(size_t)t * (Dn / 4)];
            acc.x += fmaxf(v.x, 0.f);
            acc.y += fmaxf(v.y, 0.f);
            acc.z += fmaxf(v.z, 0.f);
            acc.w += fmaxf(v.w, 0.f);
        }
    }
    float* sp = s + (size_t)b * Dn + tid * 4;
    atomicAdd(sp + 0, acc.x);
    atomicAdd(sp + 1, acc.y);
    atomicAdd(sp + 2, acc.z);
    atomicAdd(sp + 3, acc.w);
}

// Kernel 3: out[b,o] = (s[b,:] . W[o,:]) / len[b] + bias[o].
// Wave-per-output: grid (64 o-groups, 32 samples), 4 waves/block, one o per wave.
// Each wave streams W[o,:] with fully-coalesced 1KB/instruction float4 loads,
// dots against LDS-staged s[b,:], then 64-lane shfl_xor reduce.
__global__ void __launch_bounds__(256) k_out(const float* __restrict__ s,
                                             const int* __restrict__ len,
                                             const float* __restrict__ W,
                                             const float* __restrict__ bias,
                                             float* __restrict__ out) {
    const int b    = blockIdx.y;
    const int og   = blockIdx.x;          // o-group of 4
    const int tid  = threadIdx.x;
    const int w    = tid >> 6;            // wave id 0..3
    const int lane = tid & 63;
    const int o    = og * 4 + w;

    __shared__ float4 sl4[Dn / 4];
    sl4[tid] = reinterpret_cast<const float4*>(s + (size_t)b * Dn)[tid];
    __syncthreads();

    const float4* w4 = reinterpret_cast<const float4*>(W + (size_t)o * Dn);
    float acc = 0.f;
#pragma unroll
    for (int i = 0; i < Dn / 4 / 64; ++i) {   // 4 iterations
        const int d4 = i * 64 + lane;
        const float4 wv = w4[d4];
        const float4 sv = sl4[d4];
        acc += wv.x * sv.x + wv.y * sv.y + wv.z * sv.z + wv.w * sv.w;
    }
#pragma unroll
    for (int off = 32; off > 0; off >>= 1)
        acc += __shfl_xor(acc, off, 64);

    if (lane == 0) {
        const float inv = 1.0f / (float)len[b];
        out[(size_t)b * On + o] = acc * inv + bias[o];
    }
}

extern "C" void kernel_launch(void* const* d_in, const int* in_sizes, int n_in,
                              void* d_out, int out_size, void* d_ws, size_t ws_size,
                              hipStream_t stream) {
    const float* feat = (const float*)d_in[0];  // [B,T,D_IN] f32
    const float* mask = (const float*)d_in[1];  // [B,T] f32
    const float* W    = (const float*)d_in[2];  // [D_OUT,D_IN] f32
    const float* bias = (const float*)d_in[3];  // [D_OUT] f32
    float* out = (float*)d_out;                 // [B,D_OUT] f32

    // ws layout: [int len[32]] (128 B, padded to 256) | [float s[32*1024]] (128 KB)
    int*   len = (int*)d_ws;
    float* s   = (float*)((char*)d_ws + 256);

    k_prep<<<Bn, 256, 0, stream>>>(mask, len, s);
    k_sum<<<Bn * TCH, 256, 0, stream>>>(feat, len, s);
    k_out<<<dim3(On / 4, Bn), 256, 0, stream>>>(s, len, W, bias, out);
}